// Round 8
// baseline (197.127 us; speedup 1.0000x reference)
//
#include <hip/hip_runtime.h>

#define C 32
#define NT 256
#define BSH 8              // 256 nodes per bucket
#define BNODE 256
#define CAPC 5632          // per-bucket capacity (mean 4096, +24 sigma)
#define SRCMASK 0x1FFFF

typedef float f32x4 __attribute__((ext_vector_type(4)));

__device__ __forceinline__ unsigned int f2bf(float f) {
    unsigned int u = __float_as_uint(f);
    return (u + 0x7FFFu + ((u >> 16) & 1u)) >> 16;   // RNE to bf16
}
__device__ __forceinline__ float bflo(unsigned int u) { return __uint_as_float(u << 16); }
__device__ __forceinline__ float bfhi(unsigned int u) { return __uint_as_float(u & 0xFFFF0000u); }

__global__ void init_cursor(int* __restrict__ cursor, int nbuck) {
    int i = blockIdx.x * blockDim.x + threadIdx.x;
    if (i < nbuck) cursor[i] = i * CAPC;
}

// Phase A: bucketize by dst>>8 (unchanged from R7 — proven).
__global__ __launch_bounds__(1024) void phaseA(const int* __restrict__ src,
                                               const int* __restrict__ dst,
                                               int* __restrict__ cursor,
                                               int* __restrict__ pk,
                                               int E, int nbuck, int chunk) {
    extern __shared__ int l[];
    int* lcnt = l;
    int* lcur = l + nbuck;
    int tid = threadIdx.x;
    for (int i = tid; i < nbuck; i += 1024) lcnt[i] = 0;
    __syncthreads();
    int base = blockIdx.x * chunk;
    int end  = min(base + chunk, E);
    for (int e = base + tid; e < end; e += 1024)
        atomicAdd(&lcnt[dst[e] >> BSH], 1);
    __syncthreads();
    for (int i = tid; i < nbuck; i += 1024) {
        int c = lcnt[i];
        lcur[i] = c ? atomicAdd(&cursor[i], c) : 0;
    }
    __syncthreads();
    for (int e = base + tid; e < end; e += 1024) {
        int d = dst[e];
        int b = d >> BSH;
        int pos = atomicAdd(&lcur[b], 1);
        pk[pos] = src[e] | ((d & (BNODE - 1)) << 17);
    }
}

// Phase B: per-bucket 512-way counting sort, key = (dst_res<<1)|(src>=NH).
// Each node's row = [A-segment (src<NH) | B-segment]. Fused x->bf16 cvt.
__global__ __launch_bounds__(512) void phaseB(int* __restrict__ pk,
                                              const int* __restrict__ cursor,
                                              int* __restrict__ row_start,
                                              int* __restrict__ idegA,
                                              int* __restrict__ ideg,
                                              const float* __restrict__ x,
                                              uint2* __restrict__ xb2,
                                              int N, int NH) {
    __shared__ int ent[CAPC];
    __shared__ int h[512];
    __shared__ int s[512];
    __shared__ int cur[512];
    int b = blockIdx.x;
    int tid = threadIdx.x;

    // fused cvt of this bucket's own x rows
    int n0 = b << BSH;
    int nvalid = min(N - n0, BNODE);
    for (int i = tid; i < nvalid * 8; i += 512) {
        int n = n0 + (i >> 3);
        int lq = i & 7;
        const float* xp = x + (size_t)n * C + lq * 4;
        uint2 r;
        r.x = f2bf(xp[0]) | (f2bf(xp[1]) << 16);
        r.y = f2bf(xp[2]) | (f2bf(xp[3]) << 16);
        xb2[(size_t)n * 8 + lq] = r;
    }

    int base = b * CAPC;
    int cnt = min(cursor[b] - base, CAPC);
    for (int i = tid; i < cnt; i += 512) ent[i] = pk[base + i];
    h[tid] = 0;
    __syncthreads();
    for (int i = tid; i < cnt; i += 512) {
        int en = ent[i];
        int k = (((unsigned)en >> 17) << 1) | ((en & SRCMASK) >= NH ? 1 : 0);
        atomicAdd(&h[k], 1);
    }
    __syncthreads();
    int v = h[tid];
    s[tid] = v;
    __syncthreads();
    for (int off = 1; off < 512; off <<= 1) {
        int u = (tid >= off) ? s[tid - off] : 0;
        __syncthreads();
        s[tid] += u;
        __syncthreads();
    }
    cur[tid] = s[tid] - v;              // exclusive prefix for key tid
    __syncthreads();
    if (tid < BNODE) {
        int n = n0 + tid;
        if (n < N) {
            int hA = h[2 * tid], hB = h[2 * tid + 1];
            row_start[n] = base + (s[2 * tid] - hA);
            idegA[n] = hA;
            ideg[n]  = hA + hB;
        }
    }
    __syncthreads();
    for (int i = tid; i < cnt; i += 512) {
        int en = ent[i];
        int k = (((unsigned)en >> 17) << 1) | ((en & SRCMASK) >= NH ? 1 : 0);
        int pos = atomicAdd(&cur[k], 1);
        pk[base + pos] = en & SRCMASK;
    }
}

// accumulate bf16 rows over pk[lo..hi) for lane-quarter lq (4 channels)
__device__ __forceinline__ void accum_seg(const uint2* __restrict__ arr,
                                          const int* __restrict__ pk,
                                          int lo, int hi, int lq,
                                          float& a0, float& a1, float& a2, float& a3) {
#define ACC4(ux, uy) { a0 += bflo(ux); a1 += bfhi(ux); a2 += bflo(uy); a3 += bfhi(uy); }
    int j = lo;
    for (; j + 7 < hi; j += 8) {
        int s0 = __builtin_nontemporal_load(&pk[j]);
        int s1 = __builtin_nontemporal_load(&pk[j + 1]);
        int s2 = __builtin_nontemporal_load(&pk[j + 2]);
        int s3 = __builtin_nontemporal_load(&pk[j + 3]);
        int s4 = __builtin_nontemporal_load(&pk[j + 4]);
        int s5 = __builtin_nontemporal_load(&pk[j + 5]);
        int s6 = __builtin_nontemporal_load(&pk[j + 6]);
        int s7 = __builtin_nontemporal_load(&pk[j + 7]);
        uint2 u0 = arr[(size_t)s0 * 8 + lq];
        uint2 u1 = arr[(size_t)s1 * 8 + lq];
        uint2 u2 = arr[(size_t)s2 * 8 + lq];
        uint2 u3 = arr[(size_t)s3 * 8 + lq];
        uint2 u4 = arr[(size_t)s4 * 8 + lq];
        uint2 u5 = arr[(size_t)s5 * 8 + lq];
        uint2 u6 = arr[(size_t)s6 * 8 + lq];
        uint2 u7 = arr[(size_t)s7 * 8 + lq];
        ACC4(u0.x, u0.y) ACC4(u1.x, u1.y) ACC4(u2.x, u2.y) ACC4(u3.x, u3.y)
        ACC4(u4.x, u4.y) ACC4(u5.x, u5.y) ACC4(u6.x, u6.y) ACC4(u7.x, u7.y)
    }
    for (; j + 1 < hi; j += 2) {
        int s0 = __builtin_nontemporal_load(&pk[j]);
        int s1 = __builtin_nontemporal_load(&pk[j + 1]);
        uint2 u0 = arr[(size_t)s0 * 8 + lq];
        uint2 u1 = arr[(size_t)s1 * 8 + lq];
        ACC4(u0.x, u0.y) ACC4(u1.x, u1.y)
    }
    if (j < hi) {
        uint2 u0 = arr[(size_t)__builtin_nontemporal_load(&pk[j]) * 8 + lq];
        ACC4(u0.x, u0.y)
    }
#undef ACC4
}

// ---- matvec 1, pass A (src<NH): partial = -sum_A, stored fp32 in t1 ----
__global__ __launch_bounds__(NT) void g1A(const uint2* __restrict__ xb2,
        const int* __restrict__ pk, const int* __restrict__ row_start,
        const int* __restrict__ idegA, float* __restrict__ t1, int N) {
    int g = blockIdx.x * blockDim.x + threadIdx.x;
    int n = g >> 3;
    if (n >= N) return;
    int lq = g & 7;
    int rs = row_start[n];
    float a0 = 0.f, a1 = 0.f, a2 = 0.f, a3 = 0.f;
    accum_seg(xb2, pk, rs, rs + idegA[n], lq, a0, a1, a2, a3);
    size_t o = (size_t)n * C + lq * 4;
    f32x4 p = { -a0, -a1, -a2, -a3 };
    __builtin_nontemporal_store(p, (f32x4*)(t1 + o));
}

// ---- matvec 1, pass B: t1 = deg*x + partial - sum_B; also emit bf16 t1 ----
__global__ __launch_bounds__(NT) void g1B(const float* __restrict__ x,
        const uint2* __restrict__ xb2, const int* __restrict__ pk,
        const int* __restrict__ row_start, const int* __restrict__ idegA,
        const int* __restrict__ ideg, float* __restrict__ t1,
        uint2* __restrict__ t1b2, int N) {
    int g = blockIdx.x * blockDim.x + threadIdx.x;
    int n = g >> 3;
    if (n >= N) return;
    int lq = g & 7;
    int rs = row_start[n];
    int dA = idegA[n];
    int dg = ideg[n];
    float a0 = 0.f, a1 = 0.f, a2 = 0.f, a3 = 0.f;
    accum_seg(xb2, pk, rs + dA, rs + dg, lq, a0, a1, a2, a3);
    size_t o = (size_t)n * C + lq * 4;
    f32x4 xv = __builtin_nontemporal_load((const f32x4*)(x + o));
    f32x4 p  = __builtin_nontemporal_load((const f32x4*)(t1 + o));
    float fdg = (float)dg;
    f32x4 tv;
    tv.x = fdg * xv.x + p.x - a0;
    tv.y = fdg * xv.y + p.y - a1;
    tv.z = fdg * xv.z + p.z - a2;
    tv.w = fdg * xv.w + p.w - a3;
    __builtin_nontemporal_store(tv, (f32x4*)(t1 + o));
    uint2 r;
    r.x = f2bf(tv.x) | (f2bf(tv.y) << 16);
    r.y = f2bf(tv.z) | (f2bf(tv.w) << 16);
    t1b2[(size_t)n * 8 + lq] = r;
}

// ---- matvec 2, pass A: partial = -sum_A over t1b2, stored in accb ----
__global__ __launch_bounds__(NT) void g2A(const uint2* __restrict__ t1b2,
        const int* __restrict__ pk, const int* __restrict__ row_start,
        const int* __restrict__ idegA, float* __restrict__ accb, int N) {
    int g = blockIdx.x * blockDim.x + threadIdx.x;
    int n = g >> 3;
    if (n >= N) return;
    int lq = g & 7;
    int rs = row_start[n];
    float a0 = 0.f, a1 = 0.f, a2 = 0.f, a3 = 0.f;
    accum_seg(t1b2, pk, rs, rs + idegA[n], lq, a0, a1, a2, a3);
    size_t o = (size_t)n * C + lq * 4;
    f32x4 p = { -a0, -a1, -a2, -a3 };
    __builtin_nontemporal_store(p, (f32x4*)(accb + o));
}

// ---- matvec 2, pass B + final: y = w0*x + w1*t1 + w2*(deg*t1 + partial - sum_B) ----
__global__ __launch_bounds__(NT) void g2B(const float* __restrict__ x,
        const float* __restrict__ t1, const uint2* __restrict__ t1b2,
        const int* __restrict__ pk, const int* __restrict__ row_start,
        const int* __restrict__ idegA, const int* __restrict__ ideg,
        const float* __restrict__ accb, const float* __restrict__ wts,
        float* __restrict__ y, int N) {
    int g = blockIdx.x * blockDim.x + threadIdx.x;
    int n = g >> 3;
    if (n >= N) return;
    int lq = g & 7;
    int rs = row_start[n];
    int dA = idegA[n];
    int dg = ideg[n];
    float a0 = 0.f, a1 = 0.f, a2 = 0.f, a3 = 0.f;
    accum_seg(t1b2, pk, rs + dA, rs + dg, lq, a0, a1, a2, a3);
    size_t o = (size_t)n * C + lq * 4;
    f32x4 xv = __builtin_nontemporal_load((const f32x4*)(x + o));
    f32x4 tv = __builtin_nontemporal_load((const f32x4*)(t1 + o));
    f32x4 p  = __builtin_nontemporal_load((const f32x4*)(accb + o));
    float w0 = wts[0], w1 = wts[1], w2 = wts[2];
    float fdg = (float)dg;
    f32x4 r;
    r.x = w0 * xv.x + w1 * tv.x + w2 * (fdg * tv.x + p.x - a0);
    r.y = w0 * xv.y + w1 * tv.y + w2 * (fdg * tv.y + p.y - a1);
    r.z = w0 * xv.z + w1 * tv.z + w2 * (fdg * tv.z + p.z - a2);
    r.w = w0 * xv.w + w1 * tv.w + w2 * (fdg * tv.w + p.w - a3);
    __builtin_nontemporal_store(r, (f32x4*)(y + o));
}

// ---- fp32 fallback (iterates full row; row ordering irrelevant) ----
__global__ __launch_bounds__(NT) void gather1_f32(const float* __restrict__ x,
        const int* __restrict__ pk, const int* __restrict__ row_start,
        const int* __restrict__ ideg, float* __restrict__ t1, int N) {
    int g = blockIdx.x * blockDim.x + threadIdx.x;
    int n = g >> 5;
    if (n >= N) return;
    int ch = g & 31;
    int rs = row_start[n], dg = ideg[n], re = rs + dg;
    float a0 = 0, a1 = 0, a2 = 0, a3 = 0;
    int j = rs;
    for (; j + 3 < re; j += 4) {
        a0 += x[(size_t)pk[j] * C + ch];     a1 += x[(size_t)pk[j + 1] * C + ch];
        a2 += x[(size_t)pk[j + 2] * C + ch]; a3 += x[(size_t)pk[j + 3] * C + ch];
    }
    for (; j < re; ++j) a0 += x[(size_t)pk[j] * C + ch];
    size_t o = (size_t)n * C + ch;
    t1[o] = (float)dg * x[o] - ((a0 + a1) + (a2 + a3));
}
__global__ __launch_bounds__(NT) void gather2_f32(const float* __restrict__ x,
        const float* __restrict__ t1, const int* __restrict__ pk,
        const int* __restrict__ row_start, const int* __restrict__ ideg,
        const float* __restrict__ wts, float* __restrict__ y, int N) {
    int g = blockIdx.x * blockDim.x + threadIdx.x;
    int n = g >> 5;
    if (n >= N) return;
    int ch = g & 31;
    int rs = row_start[n], dg = ideg[n], re = rs + dg;
    float a0 = 0, a1 = 0, a2 = 0, a3 = 0;
    int j = rs;
    for (; j + 3 < re; j += 4) {
        a0 += t1[(size_t)pk[j] * C + ch];     a1 += t1[(size_t)pk[j + 1] * C + ch];
        a2 += t1[(size_t)pk[j + 2] * C + ch]; a3 += t1[(size_t)pk[j + 3] * C + ch];
    }
    for (; j < re; ++j) a0 += t1[(size_t)pk[j] * C + ch];
    size_t o = (size_t)n * C + ch;
    float tv = t1[o];
    y[o] = wts[0] * x[o] + wts[1] * tv + wts[2] * ((float)dg * tv - ((a0 + a1) + (a2 + a3)));
}

extern "C" void kernel_launch(void* const* d_in, const int* in_sizes, int n_in,
                              void* d_out, int out_size, void* d_ws, size_t ws_size,
                              hipStream_t stream) {
    const float* x    = (const float*)d_in[0];
    const float* wts  = (const float*)d_in[1];
    const int*   esrc = (const int*)d_in[2];
    const int*   edst = (const int*)d_in[3];
    float*       y    = (float*)d_out;

    const int N = in_sizes[0] / C;                 // 100000
    const int E = in_sizes[2];                     // 1600000
    const int NH = N / 2;                          // src-half split point
    const int nbuck = (N + BNODE - 1) >> BSH;      // 391
    const int nc = N * C;

    char* p = (char*)d_ws;
    auto align16 = [](size_t s) { return (s + 15) & ~(size_t)15; };
    int* cursor    = (int*)p; p += align16((size_t)nbuck * 4);
    int* row_start = (int*)p; p += align16((size_t)N * 4);
    int* idegA     = (int*)p; p += align16((size_t)N * 4);
    int* ideg      = (int*)p; p += align16((size_t)N * 4);
    int* pk        = (int*)p; p += align16((size_t)nbuck * CAPC * 4);
    float* t1      = (float*)p; p += align16((size_t)nc * 4);
    float* accb    = (float*)p; p += align16((size_t)nc * 4);
    uint2* xb2     = (uint2*)p; p += align16((size_t)nc * 2);
    uint2* t1b2    = (uint2*)p; p += align16((size_t)nc * 2);
    bool bf_ok = (size_t)(p - (char*)d_ws) <= ws_size;

    init_cursor<<<(nbuck + NT - 1) / NT, NT, 0, stream>>>(cursor, nbuck);

    const int ABLK = 256;
    const int chunk = (E + ABLK - 1) / ABLK;
    const size_t lds_a = (size_t)nbuck * 2 * 4;
    phaseA<<<ABLK, 1024, lds_a, stream>>>(esrc, edst, cursor, pk, E, nbuck, chunk);
    phaseB<<<nbuck, 512, 0, stream>>>(pk, cursor, row_start, idegA, ideg, x, xb2, N, NH);

    if (bf_ok) {
        const int gblocks = ((size_t)N * 8 + NT - 1) / NT;
        g1A<<<gblocks, NT, 0, stream>>>(xb2, pk, row_start, idegA, t1, N);
        g1B<<<gblocks, NT, 0, stream>>>(x, xb2, pk, row_start, idegA, ideg, t1, t1b2, N);
        g2A<<<gblocks, NT, 0, stream>>>(t1b2, pk, row_start, idegA, accb, N);
        g2B<<<gblocks, NT, 0, stream>>>(x, t1, t1b2, pk, row_start, idegA, ideg, accb, wts, y, N);
    } else {
        const int gblocks = ((size_t)N * 32 + NT - 1) / NT;
        gather1_f32<<<gblocks, NT, 0, stream>>>(x, pk, row_start, ideg, t1, N);
        gather2_f32<<<gblocks, NT, 0, stream>>>(x, t1, pk, row_start, ideg, wts, y, N);
    }
}